// Round 11
// baseline (5853.876 us; speedup 1.0000x reference)
//
#include <hip/hip_runtime.h>

#define H      51
#define T_IN   512
#define T_TOT  576
#define PH     56            // fp16 row pitch (halfs) -> 112 B (16B-aligned rows)
#define NR     204           // rows per matrix (4 gates x 51)
// LDS: FOUR fp16 matrices (Wih2, Whh2, Wih3, Whh3); Whh1 lives in registers.
#define LDSB   (4 * NR * PH * 2)     // 91,392 B -> 1 block/CU

typedef _Float16 h8 __attribute__((ext_vector_type(8)));

__device__ __forceinline__ float bf2f(unsigned short u) {
    return __uint_as_float(((unsigned int)u) << 16);
}
__device__ __forceinline__ unsigned short f2bf(float f) {
    unsigned int u = __float_as_uint(f);
    u += 0x7fffu + ((u >> 16) & 1u);
    return (unsigned short)(u >> 16);
}
__device__ __forceinline__ float wget(const void* p, int i, bool is16) {
    return is16 ? bf2f(((const unsigned short*)p)[i]) : ((const float*)p)[i];
}
__device__ __forceinline__ float rl(float v, int k) {
    return __uint_as_float((unsigned int)__builtin_amdgcn_readlane((int)__float_as_uint(v), k));
}
__device__ __forceinline__ float sigm(float x) {
    x = fminf(fmaxf(x, -30.f), 30.f);
    return 1.f / (1.f + __expf(-x));
}
__device__ __forceinline__ float tanh_f(float x) {
    x = fminf(fmaxf(x, -15.f), 15.f);
    float e = __expf(2.f * x);
    return (e - 1.f) / (e + 1.f);
}
__device__ __forceinline__ h8 ldw1(const void* p, bool is16, int row, int kb) {
    h8 v;
#pragma unroll
    for (int i = 0; i < 8; ++i) {
        int k = 8 * kb + i;
        v[i] = (k < H) ? (_Float16)wget(p, row * H + k, is16) : (_Float16)0.f;
    }
    return v;
}
#define SBAR() __builtin_amdgcn_sched_barrier(0)

// Round-11: r10's element-per-wave zero-barrier kernel (2,740us, validated)
// with the measured LDS-bandwidth term attacked (was ~6,000 of 11,400
// cycles/step/CU: 188 b128 reads x 4 waves x 8cy, 4x-redundant by design):
//  (1) Whh1 -> 28 persistent fp16 h8 REGISTERS (112 VGPR; r10 sat at 88 with
//      168 idle) -> L1 has zero LDS reads;
//  (2) Wih3/Whh3 -> fp16 LDS (precision scheme r9/r10-validated: absmax was
//      bit-identical to fp32 rounds) -> L3 reads halved;
//  (3) lanes >= 51 masked out of compute (DS serves active lanes only;
//      their h stays 0 and wlin=0 keeps the head reduce exact);
//  (4) L1->L2 fence dropped (L1 is loadless; L2 loads prefetch under L1 FMA);
//      all other SBAR fences kept (r10-proven anti-spill discipline).
// New traffic: 112 reads/wave/step (~2,900 LDS cy/CU, balancing ~2,900 VALU).
// Canaries: FETCH ~2MB (spill), absmax ~4.9e-4 (fp16-W3 validity).
extern "C" __global__ void __launch_bounds__(256)
__attribute__((amdgpu_waves_per_eu(2, 2)))
lstm3_kernel(const void* g_in,  const void* g_Wih1, const void* g_Whh1,
             const void* g_bih1, const void* g_bhh1,
             const void* g_Wih2, const void* g_Whh2, const void* g_bih2, const void* g_bhh2,
             const void* g_Wih3, const void* g_Whh3, const void* g_bih3, const void* g_bhh3,
             const void* g_Wlin, const void* g_blin, void* g_out)
{
    extern __shared__ char smraw[];
    _Float16* W2i = (_Float16*)smraw;
    _Float16* W2h = W2i + NR * PH;
    _Float16* W3i = W2h + NR * PH;
    _Float16* W3h = W3i + NR * PH;

    const int tid  = threadIdx.x;
    const int lane = tid & 63;
    const int wid  = tid >> 6;
    const int e    = blockIdx.x * 4 + wid;              // my batch element
    const int jeff = (lane < H) ? lane : (H - 1);

    // ---- dtype sniff (proven: resolves fp32 on this harness)
    bool is16 = true;
    {
        const unsigned short* p = (const unsigned short*)g_Wih1;
        for (int i = 0; i < 204; ++i) {
            float v = fabsf(bf2f(p[i]));
            if (!(v < 0.2f)) is16 = false;
        }
    }

    // ---- LDS staging (once; amortized over 576 steps)
    for (int i = tid; i < NR * PH; i += 256) {
        int r = i / PH, k = i - r * PH;
        bool v = (k < H);
        W2i[i] = v ? (_Float16)wget(g_Wih2, r * H + k, is16) : (_Float16)0.f;
        W2h[i] = v ? (_Float16)wget(g_Whh2, r * H + k, is16) : (_Float16)0.f;
        W3i[i] = v ? (_Float16)wget(g_Wih3, r * H + k, is16) : (_Float16)0.f;
        W3h[i] = v ? (_Float16)wget(g_Whh3, r * H + k, is16) : (_Float16)0.f;
    }
    __syncthreads();      // the ONLY barrier in the kernel

    // ---- Whh1 -> persistent registers (fp16 packed, 28 x h8 = 112 VGPR)
#define LW1(g, kb) ldw1(g_Whh1, is16, (g) * H + jeff, kb)
    const h8 w10_0=LW1(0,0), w10_1=LW1(0,1), w10_2=LW1(0,2), w10_3=LW1(0,3),
             w10_4=LW1(0,4), w10_5=LW1(0,5), w10_6=LW1(0,6);
    const h8 w11_0=LW1(1,0), w11_1=LW1(1,1), w11_2=LW1(1,2), w11_3=LW1(1,3),
             w11_4=LW1(1,4), w11_5=LW1(1,5), w11_6=LW1(1,6);
    const h8 w12_0=LW1(2,0), w12_1=LW1(2,1), w12_2=LW1(2,2), w12_3=LW1(2,3),
             w12_4=LW1(2,4), w12_5=LW1(2,5), w12_6=LW1(2,6);
    const h8 w13_0=LW1(3,0), w13_1=LW1(3,1), w13_2=LW1(3,2), w13_3=LW1(3,3),
             w13_4=LW1(3,4), w13_5=LW1(3,5), w13_6=LW1(3,6);

    // ---- per-lane constants (row jeff of each gate)
    const float b1_0 = wget(g_bih1, 0*H+jeff, is16) + wget(g_bhh1, 0*H+jeff, is16);
    const float b1_1 = wget(g_bih1, 1*H+jeff, is16) + wget(g_bhh1, 1*H+jeff, is16);
    const float b1_2 = wget(g_bih1, 2*H+jeff, is16) + wget(g_bhh1, 2*H+jeff, is16);
    const float b1_3 = wget(g_bih1, 3*H+jeff, is16) + wget(g_bhh1, 3*H+jeff, is16);
    const float b2_0 = wget(g_bih2, 0*H+jeff, is16) + wget(g_bhh2, 0*H+jeff, is16);
    const float b2_1 = wget(g_bih2, 1*H+jeff, is16) + wget(g_bhh2, 1*H+jeff, is16);
    const float b2_2 = wget(g_bih2, 2*H+jeff, is16) + wget(g_bhh2, 2*H+jeff, is16);
    const float b2_3 = wget(g_bih2, 3*H+jeff, is16) + wget(g_bhh2, 3*H+jeff, is16);
    const float b3_0 = wget(g_bih3, 0*H+jeff, is16) + wget(g_bhh3, 0*H+jeff, is16);
    const float b3_1 = wget(g_bih3, 1*H+jeff, is16) + wget(g_bhh3, 1*H+jeff, is16);
    const float b3_2 = wget(g_bih3, 2*H+jeff, is16) + wget(g_bhh3, 2*H+jeff, is16);
    const float b3_3 = wget(g_bih3, 3*H+jeff, is16) + wget(g_bhh3, 3*H+jeff, is16);
    const float wi1_0 = wget(g_Wih1, 0*H+jeff, is16);
    const float wi1_1 = wget(g_Wih1, 1*H+jeff, is16);
    const float wi1_2 = wget(g_Wih1, 2*H+jeff, is16);
    const float wi1_3 = wget(g_Wih1, 3*H+jeff, is16);
    const float wlin  = (lane < H) ? wget(g_Wlin, lane, is16) : 0.f;
    const float blin  = wget(g_blin, 0, is16);

    // ---- 4 per-lane base pointers; gate/slot offsets are immediates
    const _Float16* R2i = W2i + jeff * PH;
    const _Float16* R2h = W2h + jeff * PH;
    const _Float16* R3i = W3i + jeff * PH;
    const _Float16* R3h = W3h + jeff * PH;
#define H8(base, g, kb)  (*(const h8*)((base) + (g) * 51 * PH + (kb) * 8))

    float h1 = 0.f, h2 = 0.f, h3 = 0.f;    // lane j holds h[j]; lanes>=H stay 0
    float c1 = 0.f, c2 = 0.f, c3 = 0.f;
    float xf = 0.f;

    const unsigned short* in16 = (const unsigned short*)g_in;
    const float*          in32 = (const float*)g_in;
    unsigned short* o16 = (unsigned short*)g_out + (size_t)e * T_TOT;
    float*          o32 = (float*)g_out + (size_t)e * T_TOT;

    // prefetch x(0)
    float xn = is16 ? bf2f(in16[(size_t)e * T_IN]) : in32[(size_t)e * T_IN];

#define ACT(cm, hv) { \
    float i_ = sigm(a0), f_ = sigm(a1), g_ = tanh_f(a2), o_ = sigm(a3); \
    cm = f_ * cm + i_ * g_; \
    hv = o_ * tanh_f(cm); }

#define L1KB(kb) { \
    _Pragma("unroll") \
    for (int i = 0; i < 8; ++i) { \
        float s = rl(h1, 8*(kb)+i); \
        a0 = fmaf((float)w10_##kb[i], s, a0); \
        a1 = fmaf((float)w11_##kb[i], s, a1); \
        a2 = fmaf((float)w12_##kb[i], s, a2); \
        a3 = fmaf((float)w13_##kb[i], s, a3); \
    } }

#pragma clang loop unroll(disable)
    for (int t = 0; t < T_TOT; ++t) {
        float x = (t < T_IN) ? xn : xf;
        if (t + 1 < T_IN)    // prefetch next x (off the dependency chain)
            xn = is16 ? bf2f(in16[(size_t)e * T_IN + t + 1])
                      : in32[(size_t)e * T_IN + t + 1];

        if (lane < H) {      // lanes >= H: no loads, no compute (h stays 0)
            // ------- layer 1: b1 + Wih1*x + Whh1 @ h1 (REGISTER fp16) -------
            float a0 = fmaf(wi1_0, x, b1_0);
            float a1 = fmaf(wi1_1, x, b1_1);
            float a2 = fmaf(wi1_2, x, b1_2);
            float a3 = fmaf(wi1_3, x, b1_3);
            L1KB(0) L1KB(1) L1KB(2) L1KB(3) L1KB(4) L1KB(5) L1KB(6)
            ACT(c1, h1)
            // (no fence here: L2's loads may prefetch under L1's FMA chain)

            // ------- layer 2: b2 + Wih2 @ h1 + Whh2 @ h2 (fp16 LDS) --------
            a0 = b2_0; a1 = b2_1; a2 = b2_2; a3 = b2_3;
#pragma unroll
            for (int kb = 0; kb < 4; ++kb) {
                h8 ui0 = H8(R2i, 0, kb), ui1 = H8(R2i, 1, kb);
                h8 ui2 = H8(R2i, 2, kb), ui3 = H8(R2i, 3, kb);
                h8 uh0 = H8(R2h, 0, kb), uh1 = H8(R2h, 1, kb);
                h8 uh2 = H8(R2h, 2, kb), uh3 = H8(R2h, 3, kb);
#pragma unroll
                for (int i = 0; i < 8; ++i) {
                    int k = 8*kb + i;
                    float s = rl(h1, k), r = rl(h2, k);
                    a0 = fmaf((float)ui0[i], s, a0); a0 = fmaf((float)uh0[i], r, a0);
                    a1 = fmaf((float)ui1[i], s, a1); a1 = fmaf((float)uh1[i], r, a1);
                    a2 = fmaf((float)ui2[i], s, a2); a2 = fmaf((float)uh2[i], r, a2);
                    a3 = fmaf((float)ui3[i], s, a3); a3 = fmaf((float)uh3[i], r, a3);
                }
            }
            SBAR();   // mid-layer fence: in-flight-load / pressure bound
#pragma unroll
            for (int kb = 4; kb < 7; ++kb) {
                h8 ui0 = H8(R2i, 0, kb), ui1 = H8(R2i, 1, kb);
                h8 ui2 = H8(R2i, 2, kb), ui3 = H8(R2i, 3, kb);
                h8 uh0 = H8(R2h, 0, kb), uh1 = H8(R2h, 1, kb);
                h8 uh2 = H8(R2h, 2, kb), uh3 = H8(R2h, 3, kb);
#pragma unroll
                for (int i = 0; i < 8; ++i) {
                    int k = 8*kb + i;
                    float s = rl(h1, k), r = rl(h2, k);
                    a0 = fmaf((float)ui0[i], s, a0); a0 = fmaf((float)uh0[i], r, a0);
                    a1 = fmaf((float)ui1[i], s, a1); a1 = fmaf((float)uh1[i], r, a1);
                    a2 = fmaf((float)ui2[i], s, a2); a2 = fmaf((float)uh2[i], r, a2);
                    a3 = fmaf((float)ui3[i], s, a3); a3 = fmaf((float)uh3[i], r, a3);
                }
            }
            ACT(c2, h2)
            SBAR();   // layer fence

            // ------- layer 3: b3 + Wih3 @ h2 + Whh3 @ h3 (fp16 LDS) --------
            a0 = b3_0; a1 = b3_1; a2 = b3_2; a3 = b3_3;
#pragma unroll
            for (int kb = 0; kb < 4; ++kb) {
                h8 ui0 = H8(R3i, 0, kb), ui1 = H8(R3i, 1, kb);
                h8 ui2 = H8(R3i, 2, kb), ui3 = H8(R3i, 3, kb);
                h8 uh0 = H8(R3h, 0, kb), uh1 = H8(R3h, 1, kb);
                h8 uh2 = H8(R3h, 2, kb), uh3 = H8(R3h, 3, kb);
#pragma unroll
                for (int i = 0; i < 8; ++i) {
                    int k = 8*kb + i;
                    float s = rl(h2, k), r = rl(h3, k);
                    a0 = fmaf((float)ui0[i], s, a0); a0 = fmaf((float)uh0[i], r, a0);
                    a1 = fmaf((float)ui1[i], s, a1); a1 = fmaf((float)uh1[i], r, a1);
                    a2 = fmaf((float)ui2[i], s, a2); a2 = fmaf((float)uh2[i], r, a2);
                    a3 = fmaf((float)ui3[i], s, a3); a3 = fmaf((float)uh3[i], r, a3);
                }
            }
            SBAR();   // mid-layer fence
#pragma unroll
            for (int kb = 4; kb < 7; ++kb) {
                h8 ui0 = H8(R3i, 0, kb), ui1 = H8(R3i, 1, kb);
                h8 ui2 = H8(R3i, 2, kb), ui3 = H8(R3i, 3, kb);
                h8 uh0 = H8(R3h, 0, kb), uh1 = H8(R3h, 1, kb);
                h8 uh2 = H8(R3h, 2, kb), uh3 = H8(R3h, 3, kb);
#pragma unroll
                for (int i = 0; i < 8; ++i) {
                    int k = 8*kb + i;
                    float s = rl(h2, k), r = rl(h3, k);
                    a0 = fmaf((float)ui0[i], s, a0); a0 = fmaf((float)uh0[i], r, a0);
                    a1 = fmaf((float)ui1[i], s, a1); a1 = fmaf((float)uh1[i], r, a1);
                    a2 = fmaf((float)ui2[i], s, a2); a2 = fmaf((float)uh2[i], r, a2);
                    a3 = fmaf((float)ui3[i], s, a3); a3 = fmaf((float)uh3[i], r, a3);
                }
            }
            ACT(c3, h3)
        }

        // ------- head: all lanes (h3=0 & wlin=0 for lanes >= H) -------------
        float hp = wlin * h3;
        hp += __shfl_xor(hp, 1, 64);  hp += __shfl_xor(hp, 2, 64);
        hp += __shfl_xor(hp, 4, 64);  hp += __shfl_xor(hp, 8, 64);
        hp += __shfl_xor(hp, 16, 64); hp += __shfl_xor(hp, 32, 64);
        float ov = hp + blin;
        xf = ov;                                 // feeds future phase, in-wave
        if (lane == 0) {
            if (is16) o16[t] = f2bf(ov);
            else      o32[t] = ov;
        }
    }
}

extern "C" void kernel_launch(void* const* d_in, const int* in_sizes, int n_in,
                              void* d_out, int out_size, void* d_ws, size_t ws_size,
                              hipStream_t stream) {
    (void)in_sizes; (void)n_in; (void)d_ws; (void)ws_size; (void)out_size;
    size_t shmem = LDSB;                     // 91,392 B -> 1 block/CU
    hipFuncSetAttribute((const void*)lstm3_kernel,
                        hipFuncAttributeMaxDynamicSharedMemorySize, (int)shmem);
    lstm3_kernel<<<dim3(256), dim3(256), shmem, stream>>>(
        d_in[0],  d_in[1],  d_in[2],  d_in[3],  d_in[4],
        d_in[5],  d_in[6],  d_in[7],  d_in[8],
        d_in[9],  d_in[10], d_in[11], d_in[12],
        d_in[13], d_in[14], d_out);
}

// Round 12
// 3603.657 us; speedup vs baseline: 1.6244x; 1.6244x over previous
//
#include <hip/hip_runtime.h>

#define H      51
#define T_IN   512
#define T_TOT  576
#define PH     56            // fp16 row pitch (halfs) -> 112 B (16B-aligned rows)
#define NR     204           // rows per matrix (4 gates x 51)
// LDS: FOUR fp16 matrices (Wih2, Whh2, Wih3, Whh3); Whh1 lives in registers.
#define LDSB   (4 * NR * PH * 2)     // 91,392 B -> 1 block/CU

typedef _Float16 h8 __attribute__((ext_vector_type(8)));

__device__ __forceinline__ float bf2f(unsigned short u) {
    return __uint_as_float(((unsigned int)u) << 16);
}
__device__ __forceinline__ unsigned short f2bf(float f) {
    unsigned int u = __float_as_uint(f);
    u += 0x7fffu + ((u >> 16) & 1u);
    return (unsigned short)(u >> 16);
}
__device__ __forceinline__ float wget(const void* p, int i, bool is16) {
    return is16 ? bf2f(((const unsigned short*)p)[i]) : ((const float*)p)[i];
}
__device__ __forceinline__ float rl(float v, int k) {
    return __uint_as_float((unsigned int)__builtin_amdgcn_readlane((int)__float_as_uint(v), k));
}
__device__ __forceinline__ float sigm(float x) {
    x = fminf(fmaxf(x, -30.f), 30.f);
    return 1.f / (1.f + __expf(-x));
}
__device__ __forceinline__ float tanh_f(float x) {
    x = fminf(fmaxf(x, -15.f), 15.f);
    float e = __expf(2.f * x);
    return (e - 1.f) / (e + 1.f);
}
__device__ __forceinline__ h8 ldw1(const void* p, bool is16, int row, int kb) {
    h8 v;
#pragma unroll
    for (int i = 0; i < 8; ++i) {
        int k = 8 * kb + i;
        v[i] = (k < H) ? (_Float16)wget(p, row * H + k, is16) : (_Float16)0.f;
    }
    return v;
}
#define SBAR() __builtin_amdgcn_sched_barrier(0)

// Round-12: round-11 with EXACTLY ONE change: amdgpu_waves_per_eu(2,2)->(1,1).
// r11's regression was a register-cap spill, not a structure failure:
// VGPR_Count pinned at 128 while demand (~200-230: 112 persistent Whh1 h8 regs
// + transients) exceeded it -> Whh1 spilled to scratch and was re-read every
// timestep (WRITE 23.6 MB, FETCH 8.7 MB, VALUBusy 27% = scratch-latency-bound).
// Cross-round evidence: every (2,2) round reports exactly 128 VGPRs; r9's
// (1,1) reported 256. This kernel is LDS-pinned to 1 block/CU = 1 wave/SIMD
// anyway (91.4 KB), so min-2-waves/EU bought nothing. (1,1) lifts the cap;
// demand ~230 fits. r11's validated pieces kept verbatim:
//  - Whh1 in 28 persistent fp16 h8 registers (L1 has zero LDS reads);
//  - Wih2/Whh2/Wih3/Whh3 fp16 LDS (absmax bit-identical to fp32 rounds);
//  - lanes >= 51 masked out of compute (bank conflicts measured 0);
//  - SBAR fence discipline + 4 base pointers (r10-proven anti-hoist bounds).
// Canaries: VGPR must rise >128 (else cap-theory dead); WRITE ~2.3 MB,
// FETCH ~2.0 MB (spill gone); dur predicted ~2,000-2,400us.
extern "C" __global__ void __launch_bounds__(256)
__attribute__((amdgpu_waves_per_eu(1, 1)))
lstm3_kernel(const void* g_in,  const void* g_Wih1, const void* g_Whh1,
             const void* g_bih1, const void* g_bhh1,
             const void* g_Wih2, const void* g_Whh2, const void* g_bih2, const void* g_bhh2,
             const void* g_Wih3, const void* g_Whh3, const void* g_bih3, const void* g_bhh3,
             const void* g_Wlin, const void* g_blin, void* g_out)
{
    extern __shared__ char smraw[];
    _Float16* W2i = (_Float16*)smraw;
    _Float16* W2h = W2i + NR * PH;
    _Float16* W3i = W2h + NR * PH;
    _Float16* W3h = W3i + NR * PH;

    const int tid  = threadIdx.x;
    const int lane = tid & 63;
    const int wid  = tid >> 6;
    const int e    = blockIdx.x * 4 + wid;              // my batch element
    const int jeff = (lane < H) ? lane : (H - 1);

    // ---- dtype sniff (proven: resolves fp32 on this harness)
    bool is16 = true;
    {
        const unsigned short* p = (const unsigned short*)g_Wih1;
        for (int i = 0; i < 204; ++i) {
            float v = fabsf(bf2f(p[i]));
            if (!(v < 0.2f)) is16 = false;
        }
    }

    // ---- LDS staging (once; amortized over 576 steps)
    for (int i = tid; i < NR * PH; i += 256) {
        int r = i / PH, k = i - r * PH;
        bool v = (k < H);
        W2i[i] = v ? (_Float16)wget(g_Wih2, r * H + k, is16) : (_Float16)0.f;
        W2h[i] = v ? (_Float16)wget(g_Whh2, r * H + k, is16) : (_Float16)0.f;
        W3i[i] = v ? (_Float16)wget(g_Wih3, r * H + k, is16) : (_Float16)0.f;
        W3h[i] = v ? (_Float16)wget(g_Whh3, r * H + k, is16) : (_Float16)0.f;
    }
    __syncthreads();      // the ONLY barrier in the kernel

    // ---- Whh1 -> persistent registers (fp16 packed, 28 x h8 = 112 VGPR)
#define LW1(g, kb) ldw1(g_Whh1, is16, (g) * H + jeff, kb)
    const h8 w10_0=LW1(0,0), w10_1=LW1(0,1), w10_2=LW1(0,2), w10_3=LW1(0,3),
             w10_4=LW1(0,4), w10_5=LW1(0,5), w10_6=LW1(0,6);
    const h8 w11_0=LW1(1,0), w11_1=LW1(1,1), w11_2=LW1(1,2), w11_3=LW1(1,3),
             w11_4=LW1(1,4), w11_5=LW1(1,5), w11_6=LW1(1,6);
    const h8 w12_0=LW1(2,0), w12_1=LW1(2,1), w12_2=LW1(2,2), w12_3=LW1(2,3),
             w12_4=LW1(2,4), w12_5=LW1(2,5), w12_6=LW1(2,6);
    const h8 w13_0=LW1(3,0), w13_1=LW1(3,1), w13_2=LW1(3,2), w13_3=LW1(3,3),
             w13_4=LW1(3,4), w13_5=LW1(3,5), w13_6=LW1(3,6);

    // ---- per-lane constants (row jeff of each gate)
    const float b1_0 = wget(g_bih1, 0*H+jeff, is16) + wget(g_bhh1, 0*H+jeff, is16);
    const float b1_1 = wget(g_bih1, 1*H+jeff, is16) + wget(g_bhh1, 1*H+jeff, is16);
    const float b1_2 = wget(g_bih1, 2*H+jeff, is16) + wget(g_bhh1, 2*H+jeff, is16);
    const float b1_3 = wget(g_bih1, 3*H+jeff, is16) + wget(g_bhh1, 3*H+jeff, is16);
    const float b2_0 = wget(g_bih2, 0*H+jeff, is16) + wget(g_bhh2, 0*H+jeff, is16);
    const float b2_1 = wget(g_bih2, 1*H+jeff, is16) + wget(g_bhh2, 1*H+jeff, is16);
    const float b2_2 = wget(g_bih2, 2*H+jeff, is16) + wget(g_bhh2, 2*H+jeff, is16);
    const float b2_3 = wget(g_bih2, 3*H+jeff, is16) + wget(g_bhh2, 3*H+jeff, is16);
    const float b3_0 = wget(g_bih3, 0*H+jeff, is16) + wget(g_bhh3, 0*H+jeff, is16);
    const float b3_1 = wget(g_bih3, 1*H+jeff, is16) + wget(g_bhh3, 1*H+jeff, is16);
    const float b3_2 = wget(g_bih3, 2*H+jeff, is16) + wget(g_bhh3, 2*H+jeff, is16);
    const float b3_3 = wget(g_bih3, 3*H+jeff, is16) + wget(g_bhh3, 3*H+jeff, is16);
    const float wi1_0 = wget(g_Wih1, 0*H+jeff, is16);
    const float wi1_1 = wget(g_Wih1, 1*H+jeff, is16);
    const float wi1_2 = wget(g_Wih1, 2*H+jeff, is16);
    const float wi1_3 = wget(g_Wih1, 3*H+jeff, is16);
    const float wlin  = (lane < H) ? wget(g_Wlin, lane, is16) : 0.f;
    const float blin  = wget(g_blin, 0, is16);

    // ---- 4 per-lane base pointers; gate/slot offsets are immediates
    const _Float16* R2i = W2i + jeff * PH;
    const _Float16* R2h = W2h + jeff * PH;
    const _Float16* R3i = W3i + jeff * PH;
    const _Float16* R3h = W3h + jeff * PH;
#define H8(base, g, kb)  (*(const h8*)((base) + (g) * 51 * PH + (kb) * 8))

    float h1 = 0.f, h2 = 0.f, h3 = 0.f;    // lane j holds h[j]; lanes>=H stay 0
    float c1 = 0.f, c2 = 0.f, c3 = 0.f;
    float xf = 0.f;

    const unsigned short* in16 = (const unsigned short*)g_in;
    const float*          in32 = (const float*)g_in;
    unsigned short* o16 = (unsigned short*)g_out + (size_t)e * T_TOT;
    float*          o32 = (float*)g_out + (size_t)e * T_TOT;

    // prefetch x(0)
    float xn = is16 ? bf2f(in16[(size_t)e * T_IN]) : in32[(size_t)e * T_IN];

#define ACT(cm, hv) { \
    float i_ = sigm(a0), f_ = sigm(a1), g_ = tanh_f(a2), o_ = sigm(a3); \
    cm = f_ * cm + i_ * g_; \
    hv = o_ * tanh_f(cm); }

#define L1KB(kb) { \
    _Pragma("unroll") \
    for (int i = 0; i < 8; ++i) { \
        float s = rl(h1, 8*(kb)+i); \
        a0 = fmaf((float)w10_##kb[i], s, a0); \
        a1 = fmaf((float)w11_##kb[i], s, a1); \
        a2 = fmaf((float)w12_##kb[i], s, a2); \
        a3 = fmaf((float)w13_##kb[i], s, a3); \
    } }

#pragma clang loop unroll(disable)
    for (int t = 0; t < T_TOT; ++t) {
        float x = (t < T_IN) ? xn : xf;
        if (t + 1 < T_IN)    // prefetch next x (off the dependency chain)
            xn = is16 ? bf2f(in16[(size_t)e * T_IN + t + 1])
                      : in32[(size_t)e * T_IN + t + 1];

        if (lane < H) {      // lanes >= H: no loads, no compute (h stays 0)
            // ------- layer 1: b1 + Wih1*x + Whh1 @ h1 (REGISTER fp16) -------
            float a0 = fmaf(wi1_0, x, b1_0);
            float a1 = fmaf(wi1_1, x, b1_1);
            float a2 = fmaf(wi1_2, x, b1_2);
            float a3 = fmaf(wi1_3, x, b1_3);
            L1KB(0) L1KB(1) L1KB(2) L1KB(3) L1KB(4) L1KB(5) L1KB(6)
            ACT(c1, h1)
            // (no fence here: L2's loads may prefetch under L1's FMA chain)

            // ------- layer 2: b2 + Wih2 @ h1 + Whh2 @ h2 (fp16 LDS) --------
            a0 = b2_0; a1 = b2_1; a2 = b2_2; a3 = b2_3;
#pragma unroll
            for (int kb = 0; kb < 4; ++kb) {
                h8 ui0 = H8(R2i, 0, kb), ui1 = H8(R2i, 1, kb);
                h8 ui2 = H8(R2i, 2, kb), ui3 = H8(R2i, 3, kb);
                h8 uh0 = H8(R2h, 0, kb), uh1 = H8(R2h, 1, kb);
                h8 uh2 = H8(R2h, 2, kb), uh3 = H8(R2h, 3, kb);
#pragma unroll
                for (int i = 0; i < 8; ++i) {
                    int k = 8*kb + i;
                    float s = rl(h1, k), r = rl(h2, k);
                    a0 = fmaf((float)ui0[i], s, a0); a0 = fmaf((float)uh0[i], r, a0);
                    a1 = fmaf((float)ui1[i], s, a1); a1 = fmaf((float)uh1[i], r, a1);
                    a2 = fmaf((float)ui2[i], s, a2); a2 = fmaf((float)uh2[i], r, a2);
                    a3 = fmaf((float)ui3[i], s, a3); a3 = fmaf((float)uh3[i], r, a3);
                }
            }
            SBAR();   // mid-layer fence: in-flight-load / pressure bound
#pragma unroll
            for (int kb = 4; kb < 7; ++kb) {
                h8 ui0 = H8(R2i, 0, kb), ui1 = H8(R2i, 1, kb);
                h8 ui2 = H8(R2i, 2, kb), ui3 = H8(R2i, 3, kb);
                h8 uh0 = H8(R2h, 0, kb), uh1 = H8(R2h, 1, kb);
                h8 uh2 = H8(R2h, 2, kb), uh3 = H8(R2h, 3, kb);
#pragma unroll
                for (int i = 0; i < 8; ++i) {
                    int k = 8*kb + i;
                    float s = rl(h1, k), r = rl(h2, k);
                    a0 = fmaf((float)ui0[i], s, a0); a0 = fmaf((float)uh0[i], r, a0);
                    a1 = fmaf((float)ui1[i], s, a1); a1 = fmaf((float)uh1[i], r, a1);
                    a2 = fmaf((float)ui2[i], s, a2); a2 = fmaf((float)uh2[i], r, a2);
                    a3 = fmaf((float)ui3[i], s, a3); a3 = fmaf((float)uh3[i], r, a3);
                }
            }
            ACT(c2, h2)
            SBAR();   // layer fence

            // ------- layer 3: b3 + Wih3 @ h2 + Whh3 @ h3 (fp16 LDS) --------
            a0 = b3_0; a1 = b3_1; a2 = b3_2; a3 = b3_3;
#pragma unroll
            for (int kb = 0; kb < 4; ++kb) {
                h8 ui0 = H8(R3i, 0, kb), ui1 = H8(R3i, 1, kb);
                h8 ui2 = H8(R3i, 2, kb), ui3 = H8(R3i, 3, kb);
                h8 uh0 = H8(R3h, 0, kb), uh1 = H8(R3h, 1, kb);
                h8 uh2 = H8(R3h, 2, kb), uh3 = H8(R3h, 3, kb);
#pragma unroll
                for (int i = 0; i < 8; ++i) {
                    int k = 8*kb + i;
                    float s = rl(h2, k), r = rl(h3, k);
                    a0 = fmaf((float)ui0[i], s, a0); a0 = fmaf((float)uh0[i], r, a0);
                    a1 = fmaf((float)ui1[i], s, a1); a1 = fmaf((float)uh1[i], r, a1);
                    a2 = fmaf((float)ui2[i], s, a2); a2 = fmaf((float)uh2[i], r, a2);
                    a3 = fmaf((float)ui3[i], s, a3); a3 = fmaf((float)uh3[i], r, a3);
                }
            }
            SBAR();   // mid-layer fence
#pragma unroll
            for (int kb = 4; kb < 7; ++kb) {
                h8 ui0 = H8(R3i, 0, kb), ui1 = H8(R3i, 1, kb);
                h8 ui2 = H8(R3i, 2, kb), ui3 = H8(R3i, 3, kb);
                h8 uh0 = H8(R3h, 0, kb), uh1 = H8(R3h, 1, kb);
                h8 uh2 = H8(R3h, 2, kb), uh3 = H8(R3h, 3, kb);
#pragma unroll
                for (int i = 0; i < 8; ++i) {
                    int k = 8*kb + i;
                    float s = rl(h2, k), r = rl(h3, k);
                    a0 = fmaf((float)ui0[i], s, a0); a0 = fmaf((float)uh0[i], r, a0);
                    a1 = fmaf((float)ui1[i], s, a1); a1 = fmaf((float)uh1[i], r, a1);
                    a2 = fmaf((float)ui2[i], s, a2); a2 = fmaf((float)uh2[i], r, a2);
                    a3 = fmaf((float)ui3[i], s, a3); a3 = fmaf((float)uh3[i], r, a3);
                }
            }
            ACT(c3, h3)
        }

        // ------- head: all lanes (h3=0 & wlin=0 for lanes >= H) -------------
        float hp = wlin * h3;
        hp += __shfl_xor(hp, 1, 64);  hp += __shfl_xor(hp, 2, 64);
        hp += __shfl_xor(hp, 4, 64);  hp += __shfl_xor(hp, 8, 64);
        hp += __shfl_xor(hp, 16, 64); hp += __shfl_xor(hp, 32, 64);
        float ov = hp + blin;
        xf = ov;                                 // feeds future phase, in-wave
        if (lane == 0) {
            if (is16) o16[t] = f2bf(ov);
            else      o32[t] = ov;
        }
    }
}

extern "C" void kernel_launch(void* const* d_in, const int* in_sizes, int n_in,
                              void* d_out, int out_size, void* d_ws, size_t ws_size,
                              hipStream_t stream) {
    (void)in_sizes; (void)n_in; (void)d_ws; (void)ws_size; (void)out_size;
    size_t shmem = LDSB;                     // 91,392 B -> 1 block/CU
    hipFuncSetAttribute((const void*)lstm3_kernel,
                        hipFuncAttributeMaxDynamicSharedMemorySize, (int)shmem);
    lstm3_kernel<<<dim3(256), dim3(256), shmem, stream>>>(
        d_in[0],  d_in[1],  d_in[2],  d_in[3],  d_in[4],
        d_in[5],  d_in[6],  d_in[7],  d_in[8],
        d_in[9],  d_in[10], d_in[11], d_in[12],
        d_in[13], d_in[14], d_out);
}

// Round 13
// 2771.703 us; speedup vs baseline: 2.1120x; 1.3002x over previous
//
#include <hip/hip_runtime.h>

#define H      51
#define T_IN   512
#define T_TOT  576
#define PH     56            // fp16 row pitch (halfs) -> 112 B (16B-aligned rows)
#define NR     204           // rows per matrix (4 gates x 51)
// LDS: FIVE fp16 matrices (Whh1, Wih2, Whh2, Wih3, Whh3).
#define LDSB   (5 * NR * PH * 2)     // 114,240 B -> 1 block/CU

typedef _Float16 h8 __attribute__((ext_vector_type(8)));

__device__ __forceinline__ float bf2f(unsigned short u) {
    return __uint_as_float(((unsigned int)u) << 16);
}
__device__ __forceinline__ unsigned short f2bf(float f) {
    unsigned int u = __float_as_uint(f);
    u += 0x7fffu + ((u >> 16) & 1u);
    return (unsigned short)(u >> 16);
}
__device__ __forceinline__ float wget(const void* p, int i, bool is16) {
    return is16 ? bf2f(((const unsigned short*)p)[i]) : ((const float*)p)[i];
}
__device__ __forceinline__ float rl(float v, int k) {
    return __uint_as_float((unsigned int)__builtin_amdgcn_readlane((int)__float_as_uint(v), k));
}
__device__ __forceinline__ float sigm(float x) {
    x = fminf(fmaxf(x, -30.f), 30.f);
    return 1.f / (1.f + __expf(-x));
}
__device__ __forceinline__ float tanh_f(float x) {
    x = fminf(fmaxf(x, -15.f), 15.f);
    float e = __expf(2.f * x);
    return (e - 1.f) / (e + 1.f);
}
#define SBAR() __builtin_amdgcn_sched_barrier(0)

// Round-13: r10's proven skeleton (2,740us best: all-LDS weights, 5 base
// pointers, SBAR fences, waves_per_eu(2,2), 88 VGPR no-spill) + ONLY the
// two r11/r12-validated wins, with the r12 poison (register-Whh1) removed:
//  (a) Wih3/Whh3 fp32 -> fp16 LDS (absmax unchanged across r11/r12):
//      L3 reads 104 -> 56; per-wave reads/step 188 -> 140;
//  (b) lane-mask (lane < H): r11/r12 measured SQ_LDS_BANK_CONFLICT == 0
//      with this mask + PH=56 layout (r10's fp32 PF=52 layout showed 1.1e8
//      = ~750 cy/step/CU), and DS serves 51 not 64 lanes (-20% lane-cycles).
// Register-Whh1 is DEAD by r12's measurement: equal absolute VALU cycles
// (extracts replace loads) but more stall (112 pinned VGPRs shrink the
// prefetch window at 1 wave/SIMD where no TLP exists).
// DS model: ~6,750 -> ~3,600 cy/step/CU; VALU ~6,600 unchanged.
// Canaries: VGPR <= 128 & FETCH ~2 MB (spill); absmax 4.88e-4 (fp16).
extern "C" __global__ void __launch_bounds__(256)
__attribute__((amdgpu_waves_per_eu(2, 2)))
lstm3_kernel(const void* g_in,  const void* g_Wih1, const void* g_Whh1,
             const void* g_bih1, const void* g_bhh1,
             const void* g_Wih2, const void* g_Whh2, const void* g_bih2, const void* g_bhh2,
             const void* g_Wih3, const void* g_Whh3, const void* g_bih3, const void* g_bhh3,
             const void* g_Wlin, const void* g_blin, void* g_out)
{
    extern __shared__ char smraw[];
    _Float16* W1h = (_Float16*)smraw;
    _Float16* W2i = W1h + NR * PH;
    _Float16* W2h = W2i + NR * PH;
    _Float16* W3i = W2h + NR * PH;
    _Float16* W3h = W3i + NR * PH;

    const int tid  = threadIdx.x;
    const int lane = tid & 63;
    const int wid  = tid >> 6;
    const int e    = blockIdx.x * 4 + wid;              // my batch element
    const int jeff = (lane < H) ? lane : (H - 1);

    // ---- dtype sniff (proven: resolves fp32 on this harness)
    bool is16 = true;
    {
        const unsigned short* p = (const unsigned short*)g_Wih1;
        for (int i = 0; i < 204; ++i) {
            float v = fabsf(bf2f(p[i]));
            if (!(v < 0.2f)) is16 = false;
        }
    }

    // ---- LDS staging (once; amortized over 576 steps)
    for (int i = tid; i < NR * PH; i += 256) {
        int r = i / PH, k = i - r * PH;
        bool v = (k < H);
        W1h[i] = v ? (_Float16)wget(g_Whh1, r * H + k, is16) : (_Float16)0.f;
        W2i[i] = v ? (_Float16)wget(g_Wih2, r * H + k, is16) : (_Float16)0.f;
        W2h[i] = v ? (_Float16)wget(g_Whh2, r * H + k, is16) : (_Float16)0.f;
        W3i[i] = v ? (_Float16)wget(g_Wih3, r * H + k, is16) : (_Float16)0.f;
        W3h[i] = v ? (_Float16)wget(g_Whh3, r * H + k, is16) : (_Float16)0.f;
    }
    __syncthreads();      // the ONLY barrier in the kernel

    // ---- per-lane constants (row jeff of each gate)
    const float b1_0 = wget(g_bih1, 0*H+jeff, is16) + wget(g_bhh1, 0*H+jeff, is16);
    const float b1_1 = wget(g_bih1, 1*H+jeff, is16) + wget(g_bhh1, 1*H+jeff, is16);
    const float b1_2 = wget(g_bih1, 2*H+jeff, is16) + wget(g_bhh1, 2*H+jeff, is16);
    const float b1_3 = wget(g_bih1, 3*H+jeff, is16) + wget(g_bhh1, 3*H+jeff, is16);
    const float b2_0 = wget(g_bih2, 0*H+jeff, is16) + wget(g_bhh2, 0*H+jeff, is16);
    const float b2_1 = wget(g_bih2, 1*H+jeff, is16) + wget(g_bhh2, 1*H+jeff, is16);
    const float b2_2 = wget(g_bih2, 2*H+jeff, is16) + wget(g_bhh2, 2*H+jeff, is16);
    const float b2_3 = wget(g_bih2, 3*H+jeff, is16) + wget(g_bhh2, 3*H+jeff, is16);
    const float b3_0 = wget(g_bih3, 0*H+jeff, is16) + wget(g_bhh3, 0*H+jeff, is16);
    const float b3_1 = wget(g_bih3, 1*H+jeff, is16) + wget(g_bhh3, 1*H+jeff, is16);
    const float b3_2 = wget(g_bih3, 2*H+jeff, is16) + wget(g_bhh3, 2*H+jeff, is16);
    const float b3_3 = wget(g_bih3, 3*H+jeff, is16) + wget(g_bhh3, 3*H+jeff, is16);
    const float wi1_0 = wget(g_Wih1, 0*H+jeff, is16);
    const float wi1_1 = wget(g_Wih1, 1*H+jeff, is16);
    const float wi1_2 = wget(g_Wih1, 2*H+jeff, is16);
    const float wi1_3 = wget(g_Wih1, 3*H+jeff, is16);
    const float wlin  = (lane < H) ? wget(g_Wlin, lane, is16) : 0.f;
    const float blin  = wget(g_blin, 0, is16);

    // ---- 5 per-lane base pointers; gate/slot offsets are immediates
    const _Float16* R1  = W1h + jeff * PH;
    const _Float16* R2i = W2i + jeff * PH;
    const _Float16* R2h = W2h + jeff * PH;
    const _Float16* R3i = W3i + jeff * PH;
    const _Float16* R3h = W3h + jeff * PH;
#define H8(base, g, kb)  (*(const h8*)((base) + (g) * 51 * PH + (kb) * 8))

    float h1 = 0.f, h2 = 0.f, h3 = 0.f;    // lane j holds h[j]; lanes>=H stay 0
    float c1 = 0.f, c2 = 0.f, c3 = 0.f;
    float xf = 0.f;

    const unsigned short* in16 = (const unsigned short*)g_in;
    const float*          in32 = (const float*)g_in;
    unsigned short* o16 = (unsigned short*)g_out + (size_t)e * T_TOT;
    float*          o32 = (float*)g_out + (size_t)e * T_TOT;

    // prefetch x(0)
    float xn = is16 ? bf2f(in16[(size_t)e * T_IN]) : in32[(size_t)e * T_IN];

#define ACT(cm, hv) { \
    float i_ = sigm(a0), f_ = sigm(a1), g_ = tanh_f(a2), o_ = sigm(a3); \
    cm = f_ * cm + i_ * g_; \
    hv = o_ * tanh_f(cm); }

#pragma clang loop unroll(disable)
    for (int t = 0; t < T_TOT; ++t) {
        float x = (t < T_IN) ? xn : xf;
        if (t + 1 < T_IN)    // prefetch next x (off the dependency chain)
            xn = is16 ? bf2f(in16[(size_t)e * T_IN + t + 1])
                      : in32[(size_t)e * T_IN + t + 1];

        if (lane < H) {      // lanes >= H: no loads, no compute (h stays 0)
            // ------- layer 1: b1 + Wih1*x + Whh1 @ h1 (fp16 LDS) ------------
            float a0 = fmaf(wi1_0, x, b1_0);
            float a1 = fmaf(wi1_1, x, b1_1);
            float a2 = fmaf(wi1_2, x, b1_2);
            float a3 = fmaf(wi1_3, x, b1_3);
#pragma unroll
            for (int kb = 0; kb < 7; ++kb) {
                h8 u0 = H8(R1, 0, kb), u1 = H8(R1, 1, kb);
                h8 u2 = H8(R1, 2, kb), u3 = H8(R1, 3, kb);
#pragma unroll
                for (int i = 0; i < 8; ++i) {
                    float s = rl(h1, 8*kb + i);  // k>=51: weight=0, h finite
                    a0 = fmaf((float)u0[i], s, a0);
                    a1 = fmaf((float)u1[i], s, a1);
                    a2 = fmaf((float)u2[i], s, a2);
                    a3 = fmaf((float)u3[i], s, a3);
                }
            }
            ACT(c1, h1)
            SBAR();   // layer fence: bounds in-flight loads / no cross hoist

            // ------- layer 2: b2 + Wih2 @ h1 + Whh2 @ h2 (fp16 LDS) --------
            a0 = b2_0; a1 = b2_1; a2 = b2_2; a3 = b2_3;
#pragma unroll
            for (int kb = 0; kb < 4; ++kb) {
                h8 ui0 = H8(R2i, 0, kb), ui1 = H8(R2i, 1, kb);
                h8 ui2 = H8(R2i, 2, kb), ui3 = H8(R2i, 3, kb);
                h8 uh0 = H8(R2h, 0, kb), uh1 = H8(R2h, 1, kb);
                h8 uh2 = H8(R2h, 2, kb), uh3 = H8(R2h, 3, kb);
#pragma unroll
                for (int i = 0; i < 8; ++i) {
                    int k = 8*kb + i;
                    float s = rl(h1, k), r = rl(h2, k);
                    a0 = fmaf((float)ui0[i], s, a0); a0 = fmaf((float)uh0[i], r, a0);
                    a1 = fmaf((float)ui1[i], s, a1); a1 = fmaf((float)uh1[i], r, a1);
                    a2 = fmaf((float)ui2[i], s, a2); a2 = fmaf((float)uh2[i], r, a2);
                    a3 = fmaf((float)ui3[i], s, a3); a3 = fmaf((float)uh3[i], r, a3);
                }
            }
            SBAR();   // mid-layer fence: pressure bound
#pragma unroll
            for (int kb = 4; kb < 7; ++kb) {
                h8 ui0 = H8(R2i, 0, kb), ui1 = H8(R2i, 1, kb);
                h8 ui2 = H8(R2i, 2, kb), ui3 = H8(R2i, 3, kb);
                h8 uh0 = H8(R2h, 0, kb), uh1 = H8(R2h, 1, kb);
                h8 uh2 = H8(R2h, 2, kb), uh3 = H8(R2h, 3, kb);
#pragma unroll
                for (int i = 0; i < 8; ++i) {
                    int k = 8*kb + i;
                    float s = rl(h1, k), r = rl(h2, k);
                    a0 = fmaf((float)ui0[i], s, a0); a0 = fmaf((float)uh0[i], r, a0);
                    a1 = fmaf((float)ui1[i], s, a1); a1 = fmaf((float)uh1[i], r, a1);
                    a2 = fmaf((float)ui2[i], s, a2); a2 = fmaf((float)uh2[i], r, a2);
                    a3 = fmaf((float)ui3[i], s, a3); a3 = fmaf((float)uh3[i], r, a3);
                }
            }
            ACT(c2, h2)
            SBAR();   // layer fence

            // ------- layer 3: b3 + Wih3 @ h2 + Whh3 @ h3 (fp16 LDS) --------
            a0 = b3_0; a1 = b3_1; a2 = b3_2; a3 = b3_3;
#pragma unroll
            for (int kb = 0; kb < 4; ++kb) {
                h8 ui0 = H8(R3i, 0, kb), ui1 = H8(R3i, 1, kb);
                h8 ui2 = H8(R3i, 2, kb), ui3 = H8(R3i, 3, kb);
                h8 uh0 = H8(R3h, 0, kb), uh1 = H8(R3h, 1, kb);
                h8 uh2 = H8(R3h, 2, kb), uh3 = H8(R3h, 3, kb);
#pragma unroll
                for (int i = 0; i < 8; ++i) {
                    int k = 8*kb + i;
                    float s = rl(h2, k), r = rl(h3, k);
                    a0 = fmaf((float)ui0[i], s, a0); a0 = fmaf((float)uh0[i], r, a0);
                    a1 = fmaf((float)ui1[i], s, a1); a1 = fmaf((float)uh1[i], r, a1);
                    a2 = fmaf((float)ui2[i], s, a2); a2 = fmaf((float)uh2[i], r, a2);
                    a3 = fmaf((float)ui3[i], s, a3); a3 = fmaf((float)uh3[i], r, a3);
                }
            }
            SBAR();   // mid-layer fence
#pragma unroll
            for (int kb = 4; kb < 7; ++kb) {
                h8 ui0 = H8(R3i, 0, kb), ui1 = H8(R3i, 1, kb);
                h8 ui2 = H8(R3i, 2, kb), ui3 = H8(R3i, 3, kb);
                h8 uh0 = H8(R3h, 0, kb), uh1 = H8(R3h, 1, kb);
                h8 uh2 = H8(R3h, 2, kb), uh3 = H8(R3h, 3, kb);
#pragma unroll
                for (int i = 0; i < 8; ++i) {
                    int k = 8*kb + i;
                    float s = rl(h2, k), r = rl(h3, k);
                    a0 = fmaf((float)ui0[i], s, a0); a0 = fmaf((float)uh0[i], r, a0);
                    a1 = fmaf((float)ui1[i], s, a1); a1 = fmaf((float)uh1[i], r, a1);
                    a2 = fmaf((float)ui2[i], s, a2); a2 = fmaf((float)uh2[i], r, a2);
                    a3 = fmaf((float)ui3[i], s, a3); a3 = fmaf((float)uh3[i], r, a3);
                }
            }
            ACT(c3, h3)
        }

        // ------- head: all lanes (h3=0 & wlin=0 for lanes >= H) -------------
        float hp = wlin * h3;
        hp += __shfl_xor(hp, 1, 64);  hp += __shfl_xor(hp, 2, 64);
        hp += __shfl_xor(hp, 4, 64);  hp += __shfl_xor(hp, 8, 64);
        hp += __shfl_xor(hp, 16, 64); hp += __shfl_xor(hp, 32, 64);
        float ov = hp + blin;
        xf = ov;                                 // feeds future phase, in-wave
        if (lane == 0) {
            if (is16) o16[t] = f2bf(ov);
            else      o32[t] = ov;
        }
    }
}

extern "C" void kernel_launch(void* const* d_in, const int* in_sizes, int n_in,
                              void* d_out, int out_size, void* d_ws, size_t ws_size,
                              hipStream_t stream) {
    (void)in_sizes; (void)n_in; (void)d_ws; (void)ws_size; (void)out_size;
    size_t shmem = LDSB;                     // 114,240 B -> 1 block/CU
    hipFuncSetAttribute((const void*)lstm3_kernel,
                        hipFuncAttributeMaxDynamicSharedMemorySize, (int)shmem);
    lstm3_kernel<<<dim3(256), dim3(256), shmem, stream>>>(
        d_in[0],  d_in[1],  d_in[2],  d_in[3],  d_in[4],
        d_in[5],  d_in[6],  d_in[7],  d_in[8],
        d_in[9],  d_in[10], d_in[11], d_in[12],
        d_in[13], d_in[14], d_out);
}

// Round 15
// 1867.095 us; speedup vs baseline: 3.1353x; 1.4845x over previous
//
#include <hip/hip_runtime.h>

#define H      51
#define T_IN   512
#define T_TOT  576
#define PH     56            // fp16 row pitch (halfs) -> 112 B (16B-aligned rows)
#define NR     204           // rows per matrix (4 gates x 51)
// LDS: FIVE fp16 matrices (Whh1, Wih2, Whh2, Wih3, Whh3).
#define LDSB   (5 * NR * PH * 2)     // 114,240 B -> 1 block/CU

typedef _Float16 h2v __attribute__((ext_vector_type(2)));

__device__ __forceinline__ float bf2f(unsigned short u) {
    return __uint_as_float(((unsigned int)u) << 16);
}
__device__ __forceinline__ unsigned short f2bf(float f) {
    unsigned int u = __float_as_uint(f);
    u += 0x7fffu + ((u >> 16) & 1u);
    return (unsigned short)(u >> 16);
}
__device__ __forceinline__ float wget(const void* p, int i, bool is16) {
    return is16 ? bf2f(((const unsigned short*)p)[i]) : ((const float*)p)[i];
}
__device__ __forceinline__ float sigm(float x) {
    x = fminf(fmaxf(x, -30.f), 30.f);
    return 1.f / (1.f + __expf(-x));
}
__device__ __forceinline__ float tanh_f(float x) {
    x = fminf(fmaxf(x, -15.f), 15.f);
    float e = __expf(2.f * x);
    return (e - 1.f) / (e + 1.f);
}
__device__ __forceinline__ h2v bch2(unsigned int u) {
    return __builtin_bit_cast(h2v, u);
}
// readlane of a packed fp16-pair register
__device__ __forceinline__ h2v rlh2(h2v v, int m) {
    unsigned int r = (unsigned int)__builtin_amdgcn_readlane(
        (int)__builtin_bit_cast(unsigned int, v), m);
    return __builtin_bit_cast(h2v, r);
}
// pack two f32 -> fp16 pair (v_cvt_pkrtz_f16_f32); bit_cast fixes the
// __fp16-vs-_Float16 vector type mismatch (same bits).
__device__ __forceinline__ h2v pkh2(float a, float b) {
    return __builtin_bit_cast(h2v, __builtin_amdgcn_cvt_pkrtz(a, b));
}
#if __has_builtin(__builtin_amdgcn_fdot2)
__device__ __forceinline__ float dot2(unsigned int w, h2v s, float acc) {
    return __builtin_amdgcn_fdot2(bch2(w), s, acc, false);
}
#else
__device__ __forceinline__ float dot2(unsigned int w, h2v s, float acc) {
    h2v wv = bch2(w);
    acc = fmaf((float)wv.x, (float)s.x, acc);
    return fmaf((float)wv.y, (float)s.y, acc);
}
#endif
#define SBAR() __builtin_amdgcn_sched_barrier(0)

// Round-14b: r13's element-per-wave zero-barrier kernel (2,771us) with the
// matmul moved to v_dot2_f32_f16 (r14 resubmit; only fix = bit_cast on
// cvt_pkrtz return type). Rationale: r13 (conflicts 0, reads -26%, dur
// unchanged) + r12 (DS<->reg swap, VALU-cycles equal) prove DS traffic is
// NON-binding; the wall is per-wave VALU issue + exposed latency at
// 1 wave/SIMD (VALUBusy 59% of the step). So cut instructions:
//  - v_dot2_f32_f16 = 2 fp16 MACs + fp32 accumulate per instruction; the
//    PH=56 LDS rows already hold adjacent-k fp16 pairs (each uint of a
//    b128 load = one pair) -> per gate per kb: 4 dot2 instead of 8 fma;
//  - packed-h broadcast: after each ACT, hp = pkh2(shfl(h,2*lane),
//    shfl(h,2*lane+1)) (3 instr/layer); readlane the PAIR -> 4 rl/kb
//    instead of 8. Matmul instr/step ~1,380 -> ~740.
// Precision: w already fp16 (validated r11-13); h->fp16 adds ~1.2e-4 rms
// per gate, sigmoid-damped; expect absmax unchanged at 4.88e-4 (bf16 ULP).
// Everything else r13-verbatim (fences, mask, pointers, (2,2), layout).
// Canaries: VGPR<=128 & FETCH ~2 MB (spill); absmax <= ~1e-3 (fp16-h).
extern "C" __global__ void __launch_bounds__(256)
__attribute__((amdgpu_waves_per_eu(2, 2)))
lstm3_kernel(const void* g_in,  const void* g_Wih1, const void* g_Whh1,
             const void* g_bih1, const void* g_bhh1,
             const void* g_Wih2, const void* g_Whh2, const void* g_bih2, const void* g_bhh2,
             const void* g_Wih3, const void* g_Whh3, const void* g_bih3, const void* g_bhh3,
             const void* g_Wlin, const void* g_blin, void* g_out)
{
    extern __shared__ char smraw[];
    _Float16* W1h = (_Float16*)smraw;
    _Float16* W2i = W1h + NR * PH;
    _Float16* W2h = W2i + NR * PH;
    _Float16* W3i = W2h + NR * PH;
    _Float16* W3h = W3i + NR * PH;

    const int tid  = threadIdx.x;
    const int lane = tid & 63;
    const int wid  = tid >> 6;
    const int e    = blockIdx.x * 4 + wid;              // my batch element
    const int jeff = (lane < H) ? lane : (H - 1);

    // ---- dtype sniff (proven: resolves correctly on this harness)
    bool is16 = true;
    {
        const unsigned short* p = (const unsigned short*)g_Wih1;
        for (int i = 0; i < 204; ++i) {
            float v = fabsf(bf2f(p[i]));
            if (!(v < 0.2f)) is16 = false;
        }
    }

    // ---- LDS staging (once; amortized over 576 steps)
    for (int i = tid; i < NR * PH; i += 256) {
        int r = i / PH, k = i - r * PH;
        bool v = (k < H);
        W1h[i] = v ? (_Float16)wget(g_Whh1, r * H + k, is16) : (_Float16)0.f;
        W2i[i] = v ? (_Float16)wget(g_Wih2, r * H + k, is16) : (_Float16)0.f;
        W2h[i] = v ? (_Float16)wget(g_Whh2, r * H + k, is16) : (_Float16)0.f;
        W3i[i] = v ? (_Float16)wget(g_Wih3, r * H + k, is16) : (_Float16)0.f;
        W3h[i] = v ? (_Float16)wget(g_Whh3, r * H + k, is16) : (_Float16)0.f;
    }
    __syncthreads();      // the ONLY barrier in the kernel

    // ---- per-lane constants (row jeff of each gate)
    const float b1_0 = wget(g_bih1, 0*H+jeff, is16) + wget(g_bhh1, 0*H+jeff, is16);
    const float b1_1 = wget(g_bih1, 1*H+jeff, is16) + wget(g_bhh1, 1*H+jeff, is16);
    const float b1_2 = wget(g_bih1, 2*H+jeff, is16) + wget(g_bhh1, 2*H+jeff, is16);
    const float b1_3 = wget(g_bih1, 3*H+jeff, is16) + wget(g_bhh1, 3*H+jeff, is16);
    const float b2_0 = wget(g_bih2, 0*H+jeff, is16) + wget(g_bhh2, 0*H+jeff, is16);
    const float b2_1 = wget(g_bih2, 1*H+jeff, is16) + wget(g_bhh2, 1*H+jeff, is16);
    const float b2_2 = wget(g_bih2, 2*H+jeff, is16) + wget(g_bhh2, 2*H+jeff, is16);
    const float b2_3 = wget(g_bih2, 3*H+jeff, is16) + wget(g_bhh2, 3*H+jeff, is16);
    const float b3_0 = wget(g_bih3, 0*H+jeff, is16) + wget(g_bhh3, 0*H+jeff, is16);
    const float b3_1 = wget(g_bih3, 1*H+jeff, is16) + wget(g_bhh3, 1*H+jeff, is16);
    const float b3_2 = wget(g_bih3, 2*H+jeff, is16) + wget(g_bhh3, 2*H+jeff, is16);
    const float b3_3 = wget(g_bih3, 3*H+jeff, is16) + wget(g_bhh3, 3*H+jeff, is16);
    const float wi1_0 = wget(g_Wih1, 0*H+jeff, is16);
    const float wi1_1 = wget(g_Wih1, 1*H+jeff, is16);
    const float wi1_2 = wget(g_Wih1, 2*H+jeff, is16);
    const float wi1_3 = wget(g_Wih1, 3*H+jeff, is16);
    const float wlin  = (lane < H) ? wget(g_Wlin, lane, is16) : 0.f;
    const float blin  = wget(g_blin, 0, is16);

    // ---- 5 per-lane base pointers; gate/slot offsets are immediates
    const _Float16* R1  = W1h + jeff * PH;
    const _Float16* R2i = W2i + jeff * PH;
    const _Float16* R2h = W2h + jeff * PH;
    const _Float16* R3i = W3i + jeff * PH;
    const _Float16* R3h = W3h + jeff * PH;
#define U4(base, g, kb)  (*(const uint4*)((base) + (g) * 51 * PH + (kb) * 8))

    float h1 = 0.f, h2 = 0.f, h3 = 0.f;    // lane j holds h[j]; lanes>=H stay 0
    float c1 = 0.f, c2 = 0.f, c3 = 0.f;
    h2v hp1 = bch2(0u), hp2 = bch2(0u), hp3 = bch2(0u);  // packed pair bcast regs
    float xf = 0.f;

    const unsigned short* in16 = (const unsigned short*)g_in;
    const float*          in32 = (const float*)g_in;
    unsigned short* o16 = (unsigned short*)g_out + (size_t)e * T_TOT;
    float*          o32 = (float*)g_out + (size_t)e * T_TOT;

    // prefetch x(0)
    float xn = is16 ? bf2f(in16[(size_t)e * T_IN]) : in32[(size_t)e * T_IN];

#define ACT(cm, hv) { \
    float i_ = sigm(a0), f_ = sigm(a1), g_ = tanh_f(a2), o_ = sigm(a3); \
    cm = f_ * cm + i_ * g_; \
    hv = o_ * tanh_f(cm); }

    // rebuild packed-pair broadcast register for h (lane m -> (h[2m],h[2m+1]))
#define PACKH(hv, hp) { \
    float he_ = __shfl(hv, 2*lane, 64); \
    float ho_ = __shfl(hv, 2*lane + 1, 64); \
    hp = pkh2(he_, ho_); }

    // one matrix's 4-gate dot block for one kb (4 pairs from hp)
#define DOTBLK(base, hp, kb) { \
    uint4 u0 = U4(base, 0, kb), u1 = U4(base, 1, kb); \
    uint4 u2 = U4(base, 2, kb), u3 = U4(base, 3, kb); \
    h2v s0 = rlh2(hp, 4*(kb)+0), s1 = rlh2(hp, 4*(kb)+1); \
    h2v s2 = rlh2(hp, 4*(kb)+2), s3 = rlh2(hp, 4*(kb)+3); \
    a0 = dot2(u0.x, s0, a0); a0 = dot2(u0.y, s1, a0); \
    a0 = dot2(u0.z, s2, a0); a0 = dot2(u0.w, s3, a0); \
    a1 = dot2(u1.x, s0, a1); a1 = dot2(u1.y, s1, a1); \
    a1 = dot2(u1.z, s2, a1); a1 = dot2(u1.w, s3, a1); \
    a2 = dot2(u2.x, s0, a2); a2 = dot2(u2.y, s1, a2); \
    a2 = dot2(u2.z, s2, a2); a2 = dot2(u2.w, s3, a2); \
    a3 = dot2(u3.x, s0, a3); a3 = dot2(u3.y, s1, a3); \
    a3 = dot2(u3.z, s2, a3); a3 = dot2(u3.w, s3, a3); }

#pragma clang loop unroll(disable)
    for (int t = 0; t < T_TOT; ++t) {
        float x = (t < T_IN) ? xn : xf;
        if (t + 1 < T_IN)    // prefetch next x (off the dependency chain)
            xn = is16 ? bf2f(in16[(size_t)e * T_IN + t + 1])
                      : in32[(size_t)e * T_IN + t + 1];

        if (lane < H) {      // lanes >= H: no loads, no compute (h stays 0)
            // ------- layer 1: b1 + Wih1*x + Whh1 @ h1 (fp16 dot2) -----------
            float a0 = fmaf(wi1_0, x, b1_0);
            float a1 = fmaf(wi1_1, x, b1_1);
            float a2 = fmaf(wi1_2, x, b1_2);
            float a3 = fmaf(wi1_3, x, b1_3);
#pragma unroll
            for (int kb = 0; kb < 7; ++kb) {
                DOTBLK(R1, hp1, kb)
            }
            ACT(c1, h1)
            PACKH(h1, hp1)
            SBAR();   // layer fence: bounds in-flight loads / no cross hoist

            // ------- layer 2: b2 + Wih2 @ h1 + Whh2 @ h2 (fp16 dot2) -------
            a0 = b2_0; a1 = b2_1; a2 = b2_2; a3 = b2_3;
#pragma unroll
            for (int kb = 0; kb < 4; ++kb) {
                DOTBLK(R2i, hp1, kb)
                DOTBLK(R2h, hp2, kb)
            }
            SBAR();   // mid-layer fence: pressure bound
#pragma unroll
            for (int kb = 4; kb < 7; ++kb) {
                DOTBLK(R2i, hp1, kb)
                DOTBLK(R2h, hp2, kb)
            }
            ACT(c2, h2)
            PACKH(h2, hp2)
            SBAR();   // layer fence

            // ------- layer 3: b3 + Wih3 @ h2 + Whh3 @ h3 (fp16 dot2) -------
            a0 = b3_0; a1 = b3_1; a2 = b3_2; a3 = b3_3;
#pragma unroll
            for (int kb = 0; kb < 4; ++kb) {
                DOTBLK(R3i, hp2, kb)
                DOTBLK(R3h, hp3, kb)
            }
            SBAR();   // mid-layer fence
#pragma unroll
            for (int kb = 4; kb < 7; ++kb) {
                DOTBLK(R3i, hp2, kb)
                DOTBLK(R3h, hp3, kb)
            }
            ACT(c3, h3)
            PACKH(h3, hp3)
        }

        // ------- head: all lanes (h3=0 & wlin=0 for lanes >= H) -------------
        float hp = wlin * h3;
        hp += __shfl_xor(hp, 1, 64);  hp += __shfl_xor(hp, 2, 64);
        hp += __shfl_xor(hp, 4, 64);  hp += __shfl_xor(hp, 8, 64);
        hp += __shfl_xor(hp, 16, 64); hp += __shfl_xor(hp, 32, 64);
        float ov = hp + blin;
        xf = ov;                                 // feeds future phase, in-wave
        if (lane == 0) {
            if (is16) o16[t] = f2bf(ov);
            else      o32[t] = ov;
        }
    }
}

extern "C" void kernel_launch(void* const* d_in, const int* in_sizes, int n_in,
                              void* d_out, int out_size, void* d_ws, size_t ws_size,
                              hipStream_t stream) {
    (void)in_sizes; (void)n_in; (void)d_ws; (void)ws_size; (void)out_size;
    size_t shmem = LDSB;                     // 114,240 B -> 1 block/CU
    hipFuncSetAttribute((const void*)lstm3_kernel,
                        hipFuncAttributeMaxDynamicSharedMemorySize, (int)shmem);
    lstm3_kernel<<<dim3(256), dim3(256), shmem, stream>>>(
        d_in[0],  d_in[1],  d_in[2],  d_in[3],  d_in[4],
        d_in[5],  d_in[6],  d_in[7],  d_in[8],
        d_in[9],  d_in[10], d_in[11], d_in[12],
        d_in[13], d_in[14], d_out);
}